// Round 14
// baseline (526.282 us; speedup 1.0000x reference)
//
#include <hip/hip_runtime.h>
#include <hip/hip_bf16.h>
#include <stdint.h>

// Problem constants
#define NN 100000
#define NE 1600000
#define DH 128
#define DOUT 32
#define NG 64
#define EPS 1e-5f

#define SCAN_BLK 1024
#define SCAN_NB ((NN + SCAN_BLK - 1) / SCAN_BLK)   // 98
#define NBUCKET 32
#define NRANGE 8
#define RANGE_SZ (NN / NRANGE)   // 12500

#define PREP_COUNT_BLKS 1024
#define PREP_GB_BLKS ((NN + 255) / 256)            // 391
#define PREP_PW_BLKS 128

#define AGG_BLOCKS 4096
#define NCHUNK 32768        // total chunks; each aggregate dispatch covers NCHUNK/2
#define HALF_CHUNK (NCHUNK / 2)

typedef __attribute__((ext_vector_type(8))) unsigned short ushort8;
typedef __attribute__((ext_vector_type(8))) short bfv8;     // MFMA A/B fragment (8 bf16)
typedef __attribute__((ext_vector_type(4))) float f32x4;    // MFMA C/D fragment
typedef __attribute__((ext_vector_type(4))) int intv4;
typedef __attribute__((ext_vector_type(2))) unsigned int uintv2;

__device__ __forceinline__ float b2f(unsigned short u) {
    return __uint_as_float(((unsigned int)u) << 16);
}
__device__ __forceinline__ unsigned int f2b(float f) {   // round-to-nearest-even, low 16 bits
    unsigned int u = __float_as_uint(f);
    return (u + 0x7fffu + ((u >> 16) & 1u)) >> 16;
}
__device__ __forceinline__ float blo(unsigned int v) { return __uint_as_float(v << 16); }
__device__ __forceinline__ float bhi(unsigned int v) { return __uint_as_float(v & 0xffff0000u); }

// ---------------- merged prep: count (XCD-sliced histogram) + graph bounds + W transpose ----------------
// Edge-stream loads are PLAIN (not nontemporal): the 12.8 MB edge array is re-read by all 8
// range-groups; L3 should serve 7 of 8 passes. (r13 lesson candidate: nt was forcing HBM re-reads.)

__global__ void k_prep(const int* __restrict__ ei_dst, int* __restrict__ cnt,
                       const int* __restrict__ batch, int* __restrict__ gfirst, int* __restrict__ glast,
                       const float* __restrict__ W1, const float* __restrict__ W2,
                       unsigned short* __restrict__ WT1, unsigned short* __restrict__ WT2) {
    int bid = blockIdx.x;
    int t = threadIdx.x;
    if (bid < PREP_COUNT_BLKS) {
        int range = bid & (NRANGE - 1);
        int lo = range * RANGE_SZ, hi = lo + RANGE_SZ;
        int i = (bid >> 3) * 256 + t;
        int stride = (PREP_COUNT_BLKS >> 3) * 256;
        const intv4* d4 = reinterpret_cast<const intv4*>(ei_dst);
        for (int e = i; e < NE / 4; e += stride) {
            intv4 d = d4[e];
            if (d.x >= lo && d.x < hi) atomicAdd(&cnt[d.x], 1);
            if (d.y >= lo && d.y < hi) atomicAdd(&cnt[d.y], 1);
            if (d.z >= lo && d.z < hi) atomicAdd(&cnt[d.z], 1);
            if (d.w >= lo && d.w < hi) atomicAdd(&cnt[d.w], 1);
        }
    } else if (bid < PREP_COUNT_BLKS + PREP_GB_BLKS) {
        int i = (bid - PREP_COUNT_BLKS) * 256 + t;
        if (i < NN) {
            int g = batch[i];
            if (i == 0 || batch[i - 1] != g) gfirst[g] = i;
            if (i == NN - 1 || batch[i + 1] != g) glast[g] = i + 1;
        }
    } else {
        int i = (bid - PREP_COUNT_BLKS - PREP_GB_BLKS) * 256 + t;   // 0..32767
        int sel = i >> 14;
        int j = i & 16383;
        int k = j >> 7, n = j & 127;
        const float* W = sel ? W2 : W1;
        unsigned short* WT = sel ? WT2 : WT1;
        WT[n * 128 + k] = (unsigned short)f2b(W[j]);
    }
}

// ---------------- scans ----------------

__global__ void k_scan_partial(const int* __restrict__ cnt, int* __restrict__ bsum) {
    __shared__ int sdata[256];
    int blk = blockIdx.x, t = threadIdx.x;
    int base = blk * SCAN_BLK + t * 4;
    int s = 0;
#pragma unroll
    for (int q = 0; q < 4; q++) { int idx = base + q; if (idx < NN) s += cnt[idx]; }
    sdata[t] = s; __syncthreads();
    for (int o = 128; o; o >>= 1) { if (t < o) sdata[t] += sdata[t + o]; __syncthreads(); }
    if (t == 0) bsum[blk] = sdata[0];
}

// merged: per-block redundant top-level scan of bsum + final scan; writes rowptr/cursor/dinv;
// block 0 also writes rowptr[NN] and gcnt.
__global__ void k_scan_final(int* __restrict__ cnt, const int* __restrict__ bsum,
                             int* __restrict__ rowptr, float* __restrict__ dinv,
                             const int* __restrict__ first, const int* __restrict__ last,
                             int* __restrict__ gcnt) {
    __shared__ int sdata[256];
    __shared__ int stop[128];
    __shared__ int sbase;
    int blk = blockIdx.x, t = threadIdx.x;

    if (t < 128) stop[t] = (t < SCAN_NB) ? bsum[t] : 0;
    __syncthreads();
    for (int o = 1; o < 128; o <<= 1) {
        int add = (t < 128 && t >= o) ? stop[t - o] : 0;
        __syncthreads();
        if (t < 128) stop[t] += add;
        __syncthreads();
    }
    if (t == 0) sbase = (blk > 0) ? stop[blk - 1] : 0;
    if (blk == 0) {
        if (t == 127) rowptr[NN] = stop[127];
        if (t < NG) gcnt[t] = last[t] - first[t];
    }
    __syncthreads();

    int base = blk * SCAN_BLK + t * 4;
    int v[4]; int s = 0;
#pragma unroll
    for (int q = 0; q < 4; q++) { int idx = base + q; v[q] = (idx < NN) ? cnt[idx] : 0; s += v[q]; }
    sdata[t] = s; __syncthreads();
    for (int o = 1; o < 256; o <<= 1) {
        int add = (t >= o) ? sdata[t - o] : 0;
        __syncthreads();
        sdata[t] += add;
        __syncthreads();
    }
    int offset = sbase + sdata[t] - s;
#pragma unroll
    for (int q = 0; q < 4; q++) {
        int idx = base + q;
        if (idx < NN) {
            rowptr[idx] = offset;
            cnt[idx] = offset;                      // cursor for k_fill
            dinv[idx] = rsqrtf((float)(v[q] + 1));  // +1 self loop
            offset += v[q];
        }
    }
}

__global__ void k_fill(const int* __restrict__ ei, int* __restrict__ cursor, int* __restrict__ csr) {
    int range = blockIdx.x & (NRANGE - 1);
    int lo = range * RANGE_SZ, hi = lo + RANGE_SZ;
    int i = (blockIdx.x >> 3) * blockDim.x + threadIdx.x;
    int stride = (gridDim.x >> 3) * blockDim.x;
    const intv4* s4 = reinterpret_cast<const intv4*>(ei);
    const intv4* d4 = reinterpret_cast<const intv4*>(ei + NE);
    for (int e = i; e < NE / 4; e += stride) {
        intv4 s = s4[e];
        intv4 d = d4[e];
        if (d.x >= lo && d.x < hi) csr[atomicAdd(&cursor[d.x], 1)] = s.x;
        if (d.y >= lo && d.y < hi) csr[atomicAdd(&cursor[d.y], 1)] = s.y;
        if (d.z >= lo && d.z < hi) csr[atomicAdd(&cursor[d.z], 1)] = s.z;
        if (d.w >= lo && d.w < hi) csr[atomicAdd(&cursor[d.w], 1)] = s.w;
    }
}

// ---------------- MFMA GEMM: C[N,128](bf16) = rowscale * (transform(A)[N,128] @ W[128,128]) ----------------

template <bool BN, typename AT>
__global__ __launch_bounds__(256) void k_gemm(const AT* __restrict__ A, const unsigned short* __restrict__ WTg,
                                              unsigned short* __restrict__ C, const float* __restrict__ rowscale,
                                              const float* __restrict__ scale, const float* __restrict__ shift) {
    __shared__ unsigned char lds[65536];
    unsigned char* As = lds;
    unsigned char* Ws = lds + 32768;
    int row0 = blockIdx.x * 128;
    int t = threadIdx.x;
    int l = t & 63;
    int w = t >> 6;

    if constexpr (sizeof(AT) == 4) {
#pragma unroll
        for (int q = 0; q < 16; q++) {
            int idx = q * 256 + t;          // float4 index over 128x32
            int r = idx >> 5, c4 = idx & 31;
            float4 v = make_float4(0.f, 0.f, 0.f, 0.f);
            if (row0 + r < NN) v = reinterpret_cast<const float4*>(A)[(size_t)(row0 + r) * 32 + c4];
            ushort4 u;
            u.x = (unsigned short)f2b(v.x);
            u.y = (unsigned short)f2b(v.y);
            u.z = (unsigned short)f2b(v.z);
            u.w = (unsigned short)f2b(v.w);
            int off = r * 256 + ((c4 * 8) ^ ((r & 7) << 4));
            *reinterpret_cast<ushort4*>(As + off) = u;
        }
    } else {
#pragma unroll
        for (int q = 0; q < 8; q++) {
            int idx = q * 256 + t;          // ushort8 index over 128x16
            int r = idx >> 4, c8 = idx & 15;
            ushort8 v = (ushort8)0;
            if (row0 + r < NN) v = reinterpret_cast<const ushort8*>(A)[(size_t)(row0 + r) * 16 + c8];
            ushort8 u;
#pragma unroll
            for (int j = 0; j < 8; j++) {
                float f = b2f(v[j]);
                if (BN) { int k = c8 * 8 + j; f = fmaxf(f * scale[k] + shift[k], 0.f); }
                u[j] = (unsigned short)f2b(f);
            }
            int off = r * 256 + ((c8 * 16) ^ ((r & 7) << 4));
            *reinterpret_cast<ushort8*>(As + off) = u;
        }
    }
#pragma unroll
    for (int q = 0; q < 8; q++) {
        int idx = q * 256 + t;              // ushort8 index over 128x16
        int n = idx >> 4, c8 = idx & 15;
        ushort8 v = reinterpret_cast<const ushort8*>(WTg)[idx];
        int off = n * 256 + ((c8 * 16) ^ ((n & 7) << 4));
        *reinterpret_cast<ushort8*>(Ws + off) = v;
    }
    __syncthreads();

    f32x4 acc[2][8];
#pragma unroll
    for (int m = 0; m < 2; m++)
#pragma unroll
        for (int n = 0; n < 8; n++) acc[m][n] = (f32x4)0.f;

    int lrow = l & 15;
    int kbyte0 = (l >> 4) * 16;   // 8 bf16 = 16 bytes
#pragma unroll
    for (int kt = 0; kt < 4; kt++) {
        int kb = kt * 64 + kbyte0;
        bfv8 a[2];
#pragma unroll
        for (int m = 0; m < 2; m++) {
            int r = w * 32 + m * 16 + lrow;
            a[m] = *reinterpret_cast<const bfv8*>(As + r * 256 + (kb ^ ((r & 7) << 4)));
        }
        bfv8 b[8];
#pragma unroll
        for (int n = 0; n < 8; n++) {
            int r = n * 16 + lrow;
            b[n] = *reinterpret_cast<const bfv8*>(Ws + r * 256 + (kb ^ ((r & 7) << 4)));
        }
#pragma unroll
        for (int m = 0; m < 2; m++)
#pragma unroll
            for (int n = 0; n < 8; n++)
                acc[m][n] = __builtin_amdgcn_mfma_f32_16x16x32_bf16(a[m], b[n], acc[m][n], 0, 0, 0);
    }

#pragma unroll
    for (int m = 0; m < 2; m++) {
#pragma unroll
        for (int rr = 0; rr < 4; rr++) {
            int grow = row0 + w * 32 + m * 16 + (l >> 4) * 4 + rr;
            if (grow < NN) {
                float rs = rowscale[grow];
#pragma unroll
                for (int n = 0; n < 8; n++) {
                    int col = n * 16 + (l & 15);
                    C[(size_t)grow * DH + col] = (unsigned short)f2b(acc[m][n][rr] * rs);
                }
            }
        }
    }
}

// ---------------- Aggregation: static strided chunks; dispatch covers [cbase, cbase+HALF_CHUNK) ----------
// Two dispatches per layer (row-disjoint: a row belongs to the chunk containing its rowptr start).
// Splitting is a DIAGNOSTIC: exposes the next-largest dispatch in rocprof top-5.

__global__ __launch_bounds__(128) void k_aggregate(const unsigned short* __restrict__ h, const int* __restrict__ rowptr,
                                                   const int* __restrict__ csr, const float* __restrict__ dinv,
                                                   unsigned short* __restrict__ agg, float* __restrict__ stats,
                                                   int cbase) {
    int lane = threadIdx.x & 63;
    int wv = threadIdx.x >> 6;
    int half = lane >> 5;
    int sl = lane & 31;
    const uintv2* h64 = reinterpret_cast<const uintv2*>(h);
    uintv2* agg64 = reinterpret_cast<uintv2*>(agg);
    int wid = blockIdx.x * 2 + wv;
    int nw = gridDim.x * 2;

    float s0 = 0.f, s1 = 0.f, s2 = 0.f, s3 = 0.f;
    float q0 = 0.f, q1 = 0.f, q2 = 0.f, q3 = 0.f;

    for (int c = cbase + wid; c < cbase + HALF_CHUNK; c += nw) {
        long long tlo = ((long long)c * NE) / NCHUNK;
        long long thi = (c == NCHUNK - 1) ? (long long)NE + 1 : (((long long)(c + 1) * NE) / NCHUNK);
        int thii = (int)thi;

        // lower_bound: first row r with rowptr[r] >= tlo
        int lo = 0, hi = NN;
        while (lo < hi) {
            int mid = (lo + hi) >> 1;
            if (rowptr[mid] < (int)tlo) lo = mid + 1; else hi = mid;
        }

        for (int i = lo; i < NN; i++) {
            int row = rowptr[i];
            if (row >= thii) break;
            int end = rowptr[i + 1];
            int len = end - row;
            float di = dinv[i];
            float a0 = 0.f, a1 = 0.f, a2 = 0.f, a3 = 0.f;
            if (half == 0) {
                uintv2 sv = h64[(size_t)i * 32 + sl];
                a0 = blo(sv.x); a1 = bhi(sv.x); a2 = blo(sv.y); a3 = bhi(sv.y);
            }
            int hc = (len + 1 - half) >> 1;   // this half-stream's edge count
            int tt = 0;
            for (; tt + 4 <= hc; tt += 4) {
                int eA = row + (tt << 1) + half;
                int n0 = csr[eA], n1 = csr[eA + 2], n2 = csr[eA + 4], n3 = csr[eA + 6];
                uintv2 v0 = h64[(size_t)n0 * 32 + sl];
                uintv2 v1 = h64[(size_t)n1 * 32 + sl];
                uintv2 v2 = h64[(size_t)n2 * 32 + sl];
                uintv2 v3 = h64[(size_t)n3 * 32 + sl];
                a0 += blo(v0.x); a1 += bhi(v0.x); a2 += blo(v0.y); a3 += bhi(v0.y);
                a0 += blo(v1.x); a1 += bhi(v1.x); a2 += blo(v1.y); a3 += bhi(v1.y);
                a0 += blo(v2.x); a1 += bhi(v2.x); a2 += blo(v2.y); a3 += bhi(v2.y);
                a0 += blo(v3.x); a1 += bhi(v3.x); a2 += blo(v3.y); a3 += bhi(v3.y);
            }
            for (; tt < hc; tt++) {
                int e = row + (tt << 1) + half;
                int n = csr[e];
                uintv2 v = h64[(size_t)n * 32 + sl];
                a0 += blo(v.x); a1 += bhi(v.x); a2 += blo(v.y); a3 += bhi(v.y);
            }
            a0 += __shfl_xor(a0, 32);
            a1 += __shfl_xor(a1, 32);
            a2 += __shfl_xor(a2, 32);
            a3 += __shfl_xor(a3, 32);
            a0 *= di; a1 *= di; a2 *= di; a3 *= di;
            if (half == 0) {
                uintv2 o;
                o.x = f2b(a0) | (f2b(a1) << 16);
                o.y = f2b(a2) | (f2b(a3) << 16);
                agg64[(size_t)i * 32 + sl] = o;
                s0 += a0; q0 += a0 * a0;
                s1 += a1; q1 += a1 * a1;
                s2 += a2; q2 += a2 * a2;
                s3 += a3; q3 += a3 * a3;
            }
        }
    }

    if (half == 0) {
        float* b = stats + (size_t)(wid & (NBUCKET - 1)) * 256;
        atomicAdd(&b[sl * 4 + 0], s0);
        atomicAdd(&b[sl * 4 + 1], s1);
        atomicAdd(&b[sl * 4 + 2], s2);
        atomicAdd(&b[sl * 4 + 3], s3);
        atomicAdd(&b[128 + sl * 4 + 0], q0);
        atomicAdd(&b[128 + sl * 4 + 1], q1);
        atomicAdd(&b[128 + sl * 4 + 2], q2);
        atomicAdd(&b[128 + sl * 4 + 3], q3);
    }
}

__global__ void k_bnparams(const float* __restrict__ stats, const float* __restrict__ gamma,
                           const float* __restrict__ beta, float* __restrict__ scale, float* __restrict__ shift) {
    int j = threadIdx.x;
    float su = 0.f, sq = 0.f;
    for (int b = 0; b < NBUCKET; b++) { su += stats[b * 256 + j]; sq += stats[b * 256 + 128 + j]; }
    float mu = su * (1.f / NN);
    float var = sq * (1.f / NN) - mu * mu;
    float rs = rsqrtf(var + EPS);
    float sc = rs * gamma[j];
    scale[j] = sc;
    shift[j] = beta[j] - mu * sc;
}

// ---------------- Pool: BN2 params computed in-block; full-row uint2 coalesced reads ----------------

#define POOL_CHUNK 256

__global__ __launch_bounds__(256) void k_pool(const unsigned short* __restrict__ agg, const int* __restrict__ batch,
                                              const float* __restrict__ stats, const float* __restrict__ gamma,
                                              const float* __restrict__ beta, float* __restrict__ pooled) {
    __shared__ float s_sc[DH], s_sh[DH];
    int t = threadIdx.x;
    if (t < DH) {
        float su = 0.f, sq = 0.f;
        for (int b = 0; b < NBUCKET; b++) { su += stats[b * 256 + t]; sq += stats[b * 256 + 128 + t]; }
        float mu = su * (1.f / NN);
        float var = sq * (1.f / NN) - mu * mu;
        float rs = rsqrtf(var + EPS);
        float sc = rs * gamma[t];
        s_sc[t] = sc;
        s_sh[t] = beta[t] - mu * sc;
    }
    __syncthreads();

    int half = t >> 5;          // 0..7
    int sl = t & 31;
    int n0 = blockIdx.x * POOL_CHUNK + half * 32;
    if (n0 >= NN) return;
    int n1 = n0 + 32; if (n1 > NN) n1 = NN;

    const uintv2* a64 = reinterpret_cast<const uintv2*>(agg);
    float sc0 = s_sc[sl * 4 + 0], sh0 = s_sh[sl * 4 + 0];
    float sc1 = s_sc[sl * 4 + 1], sh1 = s_sh[sl * 4 + 1];
    float sc2 = s_sc[sl * 4 + 2], sh2 = s_sh[sl * 4 + 2];
    float sc3 = s_sc[sl * 4 + 3], sh3 = s_sh[sl * 4 + 3];

    int gcur = batch[n0];
    float a0 = 0.f, a1 = 0.f, a2 = 0.f, a3 = 0.f;
    for (int i = n0; i < n1; i++) {
        int g = batch[i];
        if (g != gcur) {
            atomicAdd(&pooled[(size_t)gcur * DH + sl * 4 + 0], a0);
            atomicAdd(&pooled[(size_t)gcur * DH + sl * 4 + 1], a1);
            atomicAdd(&pooled[(size_t)gcur * DH + sl * 4 + 2], a2);
            atomicAdd(&pooled[(size_t)gcur * DH + sl * 4 + 3], a3);
            a0 = a1 = a2 = a3 = 0.f; gcur = g;
        }
        uintv2 v = a64[(size_t)i * 32 + sl];
        a0 += fmaxf(blo(v.x) * sc0 + sh0, 0.f);
        a1 += fmaxf(bhi(v.x) * sc1 + sh1, 0.f);
        a2 += fmaxf(blo(v.y) * sc2 + sh2, 0.f);
        a3 += fmaxf(bhi(v.y) * sc3 + sh3, 0.f);
    }
    atomicAdd(&pooled[(size_t)gcur * DH + sl * 4 + 0], a0);
    atomicAdd(&pooled[(size_t)gcur * DH + sl * 4 + 1], a1);
    atomicAdd(&pooled[(size_t)gcur * DH + sl * 4 + 2], a2);
    atomicAdd(&pooled[(size_t)gcur * DH + sl * 4 + 3], a3);
}

// ---------------- Head ----------------

__global__ __launch_bounds__(128) void k_head(const float* __restrict__ pooled, const int* __restrict__ gcnt,
                                              const float* __restrict__ fw1, const float* __restrict__ fb1,
                                              const float* __restrict__ fw2, const float* __restrict__ fb2,
                                              float* __restrict__ out) {
    __shared__ float p[DH];
    __shared__ float z[DH];
    int g = blockIdx.x;
    int j = threadIdx.x;
    float cnt = (float)max(gcnt[g], 1);
    p[j] = pooled[(size_t)g * DH + j] / cnt;
    __syncthreads();
    float a = fb1[j];
    for (int k = 0; k < DH; k++) a += p[k] * fw1[k * DH + j];
    z[j] = fmaxf(a, 0.f);
    __syncthreads();
    if (j < DOUT) {
        float l = fb2[j];
        for (int k = 0; k < DH; k++) l += z[k] * fw2[k * DOUT + j];
        float m = l;
        for (int o = 16; o; o >>= 1) m = fmaxf(m, __shfl_xor(m, o, 32));
        float e = expf(l - m);
        float s = e;
        for (int o = 16; o; o >>= 1) s += __shfl_xor(s, o, 32);
        out[(size_t)g * DOUT + j] = e / s;
    }
}

// ---------------- launch ----------------

static inline char* align256p(char* p) {
    return (char*)(((uintptr_t)p + 255) & ~(uintptr_t)255);
}

extern "C" void kernel_launch(void* const* d_in, const int* in_sizes, int n_in,
                              void* d_out, int out_size, void* d_ws, size_t ws_size,
                              hipStream_t stream) {
    const float* x     = (const float*)d_in[0];
    const int*   ei    = (const int*)d_in[1];    // int32 per harness convention
    const int*   batch = (const int*)d_in[2];
    const float* W1    = (const float*)d_in[3];
    const float* W2    = (const float*)d_in[5];
    const float* g1    = (const float*)d_in[7];
    const float* be1   = (const float*)d_in[8];
    const float* g2    = (const float*)d_in[9];
    const float* be2   = (const float*)d_in[10];
    const float* fw1   = (const float*)d_in[11];
    const float* fb1   = (const float*)d_in[12];
    const float* fw2   = (const float*)d_in[13];
    const float* fb2   = (const float*)d_in[14];
    float* out = (float*)d_out;

    // workspace carve-up
    char* w = (char*)d_ws;
    unsigned short* hbuf = (unsigned short*)w;  w += (size_t)NN * DH * 2;
    unsigned short* abuf = (unsigned short*)w;  w += (size_t)NN * DH * 2;
    int*   csr    = (int*)w;    w += (size_t)NE * 4;
    int*   rowptr = (int*)w;    w += (size_t)(NN + 1) * 4;  w = align256p(w);
    float* dinv   = (float*)w;  w += (size_t)NN * 4;
    int*   bsum   = (int*)w;    w += 512 * 4;
    float* scale1 = (float*)w;  w += DH * 4;
    float* shift1 = (float*)w;  w += DH * 4;
    unsigned short* WT1g = (unsigned short*)w;  w += (size_t)DH * DH * 2;
    unsigned short* WT2g = (unsigned short*)w;  w += (size_t)DH * DH * 2;
    w = align256p(w);
    char* zstart  = w;
    int*   cnt    = (int*)w;    w += (size_t)NN * 4;   // also the fill cursor
    int*   gfirst = (int*)w;    w += 64 * 4;
    int*   glast  = (int*)w;    w += 64 * 4;
    int*   gcnt   = (int*)w;    w += 64 * 4;
    float* stats1 = (float*)w;  w += (size_t)NBUCKET * 256 * 4;
    float* stats2 = (float*)w;  w += (size_t)NBUCKET * 256 * 4;
    float* pooled = (float*)w;  w += (size_t)NG * DH * 4;
    size_t zbytes = (size_t)(w - zstart);
    size_t need = (size_t)(w - (char*)d_ws);
    if (ws_size < need) return;   // diagnostic: clean absmax-fail instead of a fault

    hipMemsetAsync(zstart, 0, zbytes, stream);

    k_prep<<<PREP_COUNT_BLKS + PREP_GB_BLKS + PREP_PW_BLKS, 256, 0, stream>>>(
        ei + NE, cnt, batch, gfirst, glast, W1, W2, WT1g, WT2g);
    k_scan_partial<<<SCAN_NB, 256, 0, stream>>>(cnt, bsum);
    k_scan_final<<<SCAN_NB, 256, 0, stream>>>(cnt, bsum, rowptr, dinv, gfirst, glast, gcnt);
    k_fill<<<1024, 256, 0, stream>>>(ei, cnt, csr);

    int gemm_grid = (NN + 127) / 128;   // 782

    // layer 1 (output pre-scaled by dinv); aggregate split into two half-chunk dispatches
    k_gemm<false, float><<<gemm_grid, 256, 0, stream>>>(x, WT1g, hbuf, dinv, nullptr, nullptr);
    k_aggregate<<<AGG_BLOCKS, 128, 0, stream>>>(hbuf, rowptr, csr, dinv, abuf, stats1, 0);
    k_aggregate<<<AGG_BLOCKS, 128, 0, stream>>>(hbuf, rowptr, csr, dinv, abuf, stats1, HALF_CHUNK);
    k_bnparams<<<1, 128, 0, stream>>>(stats1, g1, be1, scale1, shift1);

    // layer 2 (BN1+ReLU fused into GEMM A-load); aggregate split likewise
    k_gemm<true, unsigned short><<<gemm_grid, 256, 0, stream>>>(abuf, WT2g, hbuf, dinv, scale1, shift1);
    k_aggregate<<<AGG_BLOCKS, 128, 0, stream>>>(hbuf, rowptr, csr, dinv, abuf, stats2, 0);
    k_aggregate<<<AGG_BLOCKS, 128, 0, stream>>>(hbuf, rowptr, csr, dinv, abuf, stats2, HALF_CHUNK);

    // pool (BN2 params computed in-block, BN2+ReLU fused) + head
    int pool_grid = (NN + POOL_CHUNK - 1) / POOL_CHUNK;   // 391
    k_pool<<<pool_grid, 256, 0, stream>>>(abuf, batch, stats2, g2, be2, pooled);
    k_head<<<NG, 128, 0, stream>>>(pooled, gcnt, fw1, fb1, fw2, fb2, out);
}

// Round 15
// 442.727 us; speedup vs baseline: 1.1887x; 1.1887x over previous
//
#include <hip/hip_runtime.h>
#include <hip/hip_bf16.h>
#include <stdint.h>

// Problem constants
#define NN 100000
#define NE 1600000
#define DH 128
#define DOUT 32
#define NG 64
#define EPS 1e-5f

#define SCAN_BLK 1024
#define SCAN_NB ((NN + SCAN_BLK - 1) / SCAN_BLK)   // 98
#define NBUCKET 32
#define NRANGE 4
#define RANGE_SZ (NN / NRANGE)   // 25000

#define PREP_COUNT_BLKS 1024
#define PREP_GB_BLKS ((NN + 255) / 256)            // 391
#define PREP_PW_BLKS 128

#define AGG_BLOCKS 4096
#define NCHUNK 32768   // static strided: 4 chunks per wave, no atomics (r11-proven)

typedef __attribute__((ext_vector_type(8))) unsigned short ushort8;
typedef __attribute__((ext_vector_type(8))) short bfv8;     // MFMA A/B fragment (8 bf16)
typedef __attribute__((ext_vector_type(4))) float f32x4;    // MFMA C/D fragment
typedef __attribute__((ext_vector_type(4))) int intv4;
typedef __attribute__((ext_vector_type(2))) unsigned int uintv2;

__device__ __forceinline__ float b2f(unsigned short u) {
    return __uint_as_float(((unsigned int)u) << 16);
}
__device__ __forceinline__ unsigned int f2b(float f) {   // round-to-nearest-even, low 16 bits
    unsigned int u = __float_as_uint(f);
    return (u + 0x7fffu + ((u >> 16) & 1u)) >> 16;
}
__device__ __forceinline__ float blo(unsigned int v) { return __uint_as_float(v << 16); }
__device__ __forceinline__ float bhi(unsigned int v) { return __uint_as_float(v & 0xffff0000u); }

// ---------------- merged prep: count (XCD-sliced histogram, NRANGE=4) + graph bounds + W transpose ------

__global__ void k_prep(const int* __restrict__ ei_dst, int* __restrict__ cnt,
                       const int* __restrict__ batch, int* __restrict__ gfirst, int* __restrict__ glast,
                       const float* __restrict__ W1, const float* __restrict__ W2,
                       unsigned short* __restrict__ WT1, unsigned short* __restrict__ WT2) {
    int bid = blockIdx.x;
    int t = threadIdx.x;
    if (bid < PREP_COUNT_BLKS) {
        int range = bid & (NRANGE - 1);
        int lo = range * RANGE_SZ, hi = lo + RANGE_SZ;
        int i = (bid >> 2) * 256 + t;
        int stride = (PREP_COUNT_BLKS >> 2) * 256;
        const intv4* d4 = reinterpret_cast<const intv4*>(ei_dst);
        for (int e = i; e < NE / 4; e += stride) {
            intv4 d = d4[e];
            if (d.x >= lo && d.x < hi) atomicAdd(&cnt[d.x], 1);
            if (d.y >= lo && d.y < hi) atomicAdd(&cnt[d.y], 1);
            if (d.z >= lo && d.z < hi) atomicAdd(&cnt[d.z], 1);
            if (d.w >= lo && d.w < hi) atomicAdd(&cnt[d.w], 1);
        }
    } else if (bid < PREP_COUNT_BLKS + PREP_GB_BLKS) {
        int i = (bid - PREP_COUNT_BLKS) * 256 + t;
        if (i < NN) {
            int g = batch[i];
            if (i == 0 || batch[i - 1] != g) gfirst[g] = i;
            if (i == NN - 1 || batch[i + 1] != g) glast[g] = i + 1;
        }
    } else {
        int i = (bid - PREP_COUNT_BLKS - PREP_GB_BLKS) * 256 + t;   // 0..32767
        int sel = i >> 14;
        int j = i & 16383;
        int k = j >> 7, n = j & 127;
        const float* W = sel ? W2 : W1;
        unsigned short* WT = sel ? WT2 : WT1;
        WT[n * 128 + k] = (unsigned short)f2b(W[j]);
    }
}

// ---------------- scans ----------------

__global__ void k_scan_partial(const int* __restrict__ cnt, int* __restrict__ bsum) {
    __shared__ int sdata[256];
    int blk = blockIdx.x, t = threadIdx.x;
    int base = blk * SCAN_BLK + t * 4;
    int s = 0;
#pragma unroll
    for (int q = 0; q < 4; q++) { int idx = base + q; if (idx < NN) s += cnt[idx]; }
    sdata[t] = s; __syncthreads();
    for (int o = 128; o; o >>= 1) { if (t < o) sdata[t] += sdata[t + o]; __syncthreads(); }
    if (t == 0) bsum[blk] = sdata[0];
}

// merged: per-block redundant top-level scan of bsum + final scan; writes rowptr/cursor/dinv;
// block 0 also writes rowptr[NN] and gcnt.
__global__ void k_scan_final(int* __restrict__ cnt, const int* __restrict__ bsum,
                             int* __restrict__ rowptr, float* __restrict__ dinv,
                             const int* __restrict__ first, const int* __restrict__ last,
                             int* __restrict__ gcnt) {
    __shared__ int sdata[256];
    __shared__ int stop[128];
    __shared__ int sbase;
    int blk = blockIdx.x, t = threadIdx.x;

    if (t < 128) stop[t] = (t < SCAN_NB) ? bsum[t] : 0;
    __syncthreads();
    for (int o = 1; o < 128; o <<= 1) {
        int add = (t < 128 && t >= o) ? stop[t - o] : 0;
        __syncthreads();
        if (t < 128) stop[t] += add;
        __syncthreads();
    }
    if (t == 0) sbase = (blk > 0) ? stop[blk - 1] : 0;
    if (blk == 0) {
        if (t == 127) rowptr[NN] = stop[127];
        if (t < NG) gcnt[t] = last[t] - first[t];
    }
    __syncthreads();

    int base = blk * SCAN_BLK + t * 4;
    int v[4]; int s = 0;
#pragma unroll
    for (int q = 0; q < 4; q++) { int idx = base + q; v[q] = (idx < NN) ? cnt[idx] : 0; s += v[q]; }
    sdata[t] = s; __syncthreads();
    for (int o = 1; o < 256; o <<= 1) {
        int add = (t >= o) ? sdata[t - o] : 0;
        __syncthreads();
        sdata[t] += add;
        __syncthreads();
    }
    int offset = sbase + sdata[t] - s;
#pragma unroll
    for (int q = 0; q < 4; q++) {
        int idx = base + q;
        if (idx < NN) {
            rowptr[idx] = offset;
            cnt[idx] = offset;                      // cursor for k_fill
            dinv[idx] = rsqrtf((float)(v[q] + 1));  // +1 self loop
            offset += v[q];
        }
    }
}

__global__ void k_fill(const int* __restrict__ ei, int* __restrict__ cursor, int* __restrict__ csr) {
    int range = blockIdx.x & (NRANGE - 1);
    int lo = range * RANGE_SZ, hi = lo + RANGE_SZ;
    int i = (blockIdx.x >> 2) * blockDim.x + threadIdx.x;
    int stride = (gridDim.x >> 2) * blockDim.x;
    const intv4* s4 = reinterpret_cast<const intv4*>(ei);
    const intv4* d4 = reinterpret_cast<const intv4*>(ei + NE);
    for (int e = i; e < NE / 4; e += stride) {
        intv4 s = s4[e];
        intv4 d = d4[e];
        if (d.x >= lo && d.x < hi) csr[atomicAdd(&cursor[d.x], 1)] = s.x;
        if (d.y >= lo && d.y < hi) csr[atomicAdd(&cursor[d.y], 1)] = s.y;
        if (d.z >= lo && d.z < hi) csr[atomicAdd(&cursor[d.z], 1)] = s.z;
        if (d.w >= lo && d.w < hi) csr[atomicAdd(&cursor[d.w], 1)] = s.w;
    }
}

// ---------------- MFMA GEMM: C[N,128](bf16) = rowscale * (transform(A)[N,128] @ W[128,128]) ----------------
// BN=true: BN scale/shift computed IN-BLOCK from bucketed stats (saves the k_bnparams launch).

template <bool BN, typename AT>
__global__ __launch_bounds__(256) void k_gemm(const AT* __restrict__ A, const unsigned short* __restrict__ WTg,
                                              unsigned short* __restrict__ C, const float* __restrict__ rowscale,
                                              const float* __restrict__ stats, const float* __restrict__ gamma,
                                              const float* __restrict__ beta) {
    __shared__ unsigned char lds[65536];
    __shared__ float s_sc[DH], s_sh[DH];
    unsigned char* As = lds;
    unsigned char* Ws = lds + 32768;
    int row0 = blockIdx.x * 128;
    int t = threadIdx.x;
    int l = t & 63;
    int w = t >> 6;

    if constexpr (BN) {
        if (t < DH) {
            float su = 0.f, sq = 0.f;
            for (int b = 0; b < NBUCKET; b++) { su += stats[b * 256 + t]; sq += stats[b * 256 + 128 + t]; }
            float mu = su * (1.f / NN);
            float var = sq * (1.f / NN) - mu * mu;
            float rs = rsqrtf(var + EPS);
            float sc = rs * gamma[t];
            s_sc[t] = sc;
            s_sh[t] = beta[t] - mu * sc;
        }
        __syncthreads();
    }

    if constexpr (sizeof(AT) == 4) {
#pragma unroll
        for (int q = 0; q < 16; q++) {
            int idx = q * 256 + t;          // float4 index over 128x32
            int r = idx >> 5, c4 = idx & 31;
            float4 v = make_float4(0.f, 0.f, 0.f, 0.f);
            if (row0 + r < NN) v = reinterpret_cast<const float4*>(A)[(size_t)(row0 + r) * 32 + c4];
            ushort4 u;
            u.x = (unsigned short)f2b(v.x);
            u.y = (unsigned short)f2b(v.y);
            u.z = (unsigned short)f2b(v.z);
            u.w = (unsigned short)f2b(v.w);
            int off = r * 256 + ((c4 * 8) ^ ((r & 7) << 4));
            *reinterpret_cast<ushort4*>(As + off) = u;
        }
    } else {
#pragma unroll
        for (int q = 0; q < 8; q++) {
            int idx = q * 256 + t;          // ushort8 index over 128x16
            int r = idx >> 4, c8 = idx & 15;
            ushort8 v = (ushort8)0;
            if (row0 + r < NN) v = reinterpret_cast<const ushort8*>(A)[(size_t)(row0 + r) * 16 + c8];
            ushort8 u;
#pragma unroll
            for (int j = 0; j < 8; j++) {
                float f = b2f(v[j]);
                if (BN) { int k = c8 * 8 + j; f = fmaxf(f * s_sc[k] + s_sh[k], 0.f); }
                u[j] = (unsigned short)f2b(f);
            }
            int off = r * 256 + ((c8 * 16) ^ ((r & 7) << 4));
            *reinterpret_cast<ushort8*>(As + off) = u;
        }
    }
#pragma unroll
    for (int q = 0; q < 8; q++) {
        int idx = q * 256 + t;              // ushort8 index over 128x16
        int n = idx >> 4, c8 = idx & 15;
        ushort8 v = reinterpret_cast<const ushort8*>(WTg)[idx];
        int off = n * 256 + ((c8 * 16) ^ ((n & 7) << 4));
        *reinterpret_cast<ushort8*>(Ws + off) = v;
    }
    __syncthreads();

    f32x4 acc[2][8];
#pragma unroll
    for (int m = 0; m < 2; m++)
#pragma unroll
        for (int n = 0; n < 8; n++) acc[m][n] = (f32x4)0.f;

    int lrow = l & 15;
    int kbyte0 = (l >> 4) * 16;   // 8 bf16 = 16 bytes
#pragma unroll
    for (int kt = 0; kt < 4; kt++) {
        int kb = kt * 64 + kbyte0;
        bfv8 a[2];
#pragma unroll
        for (int m = 0; m < 2; m++) {
            int r = w * 32 + m * 16 + lrow;
            a[m] = *reinterpret_cast<const bfv8*>(As + r * 256 + (kb ^ ((r & 7) << 4)));
        }
        bfv8 b[8];
#pragma unroll
        for (int n = 0; n < 8; n++) {
            int r = n * 16 + lrow;
            b[n] = *reinterpret_cast<const bfv8*>(Ws + r * 256 + (kb ^ ((r & 7) << 4)));
        }
#pragma unroll
        for (int m = 0; m < 2; m++)
#pragma unroll
            for (int n = 0; n < 8; n++)
                acc[m][n] = __builtin_amdgcn_mfma_f32_16x16x32_bf16(a[m], b[n], acc[m][n], 0, 0, 0);
    }

#pragma unroll
    for (int m = 0; m < 2; m++) {
#pragma unroll
        for (int rr = 0; rr < 4; rr++) {
            int grow = row0 + w * 32 + m * 16 + (l >> 4) * 4 + rr;
            if (grow < NN) {
                float rs = rowscale[grow];
#pragma unroll
                for (int n = 0; n < 8; n++) {
                    int col = n * 16 + (l & 15);
                    C[(size_t)grow * DH + col] = (unsigned short)f2b(acc[m][n][rr] * rs);
                }
            }
        }
    }
}

// ---------------- Aggregation: STATIC STRIDED chunks (4 per wave, no atomics) — r11-exact ----------

__global__ __launch_bounds__(128) void k_aggregate(const unsigned short* __restrict__ h, const int* __restrict__ rowptr,
                                                   const int* __restrict__ csr, const float* __restrict__ dinv,
                                                   unsigned short* __restrict__ agg, float* __restrict__ stats) {
    int lane = threadIdx.x & 63;
    int wv = threadIdx.x >> 6;
    int half = lane >> 5;
    int sl = lane & 31;
    const uintv2* h64 = reinterpret_cast<const uintv2*>(h);
    uintv2* agg64 = reinterpret_cast<uintv2*>(agg);
    int wid = blockIdx.x * 2 + wv;
    int nw = gridDim.x * 2;

    float s0 = 0.f, s1 = 0.f, s2 = 0.f, s3 = 0.f;
    float q0 = 0.f, q1 = 0.f, q2 = 0.f, q3 = 0.f;

    for (int c = wid; c < NCHUNK; c += nw) {
        long long tlo = ((long long)c * NE) / NCHUNK;
        long long thi = (c == NCHUNK - 1) ? (long long)NE + 1 : (((long long)(c + 1) * NE) / NCHUNK);
        int thii = (int)thi;

        // lower_bound: first row r with rowptr[r] >= tlo
        int lo = 0, hi = NN;
        while (lo < hi) {
            int mid = (lo + hi) >> 1;
            if (rowptr[mid] < (int)tlo) lo = mid + 1; else hi = mid;
        }

        for (int i = lo; i < NN; i++) {
            int row = rowptr[i];
            if (row >= thii) break;
            int end = rowptr[i + 1];
            int len = end - row;
            float di = dinv[i];
            float a0 = 0.f, a1 = 0.f, a2 = 0.f, a3 = 0.f;
            if (half == 0) {
                uintv2 sv = h64[(size_t)i * 32 + sl];
                a0 = blo(sv.x); a1 = bhi(sv.x); a2 = blo(sv.y); a3 = bhi(sv.y);
            }
            int hc = (len + 1 - half) >> 1;   // this half-stream's edge count
            int tt = 0;
            for (; tt + 4 <= hc; tt += 4) {
                int eA = row + (tt << 1) + half;
                int n0 = csr[eA], n1 = csr[eA + 2], n2 = csr[eA + 4], n3 = csr[eA + 6];
                uintv2 v0 = h64[(size_t)n0 * 32 + sl];
                uintv2 v1 = h64[(size_t)n1 * 32 + sl];
                uintv2 v2 = h64[(size_t)n2 * 32 + sl];
                uintv2 v3 = h64[(size_t)n3 * 32 + sl];
                a0 += blo(v0.x); a1 += bhi(v0.x); a2 += blo(v0.y); a3 += bhi(v0.y);
                a0 += blo(v1.x); a1 += bhi(v1.x); a2 += blo(v1.y); a3 += bhi(v1.y);
                a0 += blo(v2.x); a1 += bhi(v2.x); a2 += blo(v2.y); a3 += bhi(v2.y);
                a0 += blo(v3.x); a1 += bhi(v3.x); a2 += blo(v3.y); a3 += bhi(v3.y);
            }
            for (; tt < hc; tt++) {
                int e = row + (tt << 1) + half;
                int n = csr[e];
                uintv2 v = h64[(size_t)n * 32 + sl];
                a0 += blo(v.x); a1 += bhi(v.x); a2 += blo(v.y); a3 += bhi(v.y);
            }
            a0 += __shfl_xor(a0, 32);
            a1 += __shfl_xor(a1, 32);
            a2 += __shfl_xor(a2, 32);
            a3 += __shfl_xor(a3, 32);
            a0 *= di; a1 *= di; a2 *= di; a3 *= di;
            if (half == 0) {
                uintv2 o;
                o.x = f2b(a0) | (f2b(a1) << 16);
                o.y = f2b(a2) | (f2b(a3) << 16);
                agg64[(size_t)i * 32 + sl] = o;
                s0 += a0; q0 += a0 * a0;
                s1 += a1; q1 += a1 * a1;
                s2 += a2; q2 += a2 * a2;
                s3 += a3; q3 += a3 * a3;
            }
        }
    }

    if (half == 0) {
        float* b = stats + (size_t)(wid & (NBUCKET - 1)) * 256;
        atomicAdd(&b[sl * 4 + 0], s0);
        atomicAdd(&b[sl * 4 + 1], s1);
        atomicAdd(&b[sl * 4 + 2], s2);
        atomicAdd(&b[sl * 4 + 3], s3);
        atomicAdd(&b[128 + sl * 4 + 0], q0);
        atomicAdd(&b[128 + sl * 4 + 1], q1);
        atomicAdd(&b[128 + sl * 4 + 2], q2);
        atomicAdd(&b[128 + sl * 4 + 3], q3);
    }
}

// ---------------- Pool: BN2 params computed in-block; full-row uint2 coalesced reads ----------------

#define POOL_CHUNK 256

__global__ __launch_bounds__(256) void k_pool(const unsigned short* __restrict__ agg, const int* __restrict__ batch,
                                              const float* __restrict__ stats, const float* __restrict__ gamma,
                                              const float* __restrict__ beta, float* __restrict__ pooled) {
    __shared__ float s_sc[DH], s_sh[DH];
    int t = threadIdx.x;
    if (t < DH) {
        float su = 0.f, sq = 0.f;
        for (int b = 0; b < NBUCKET; b++) { su += stats[b * 256 + t]; sq += stats[b * 256 + 128 + t]; }
        float mu = su * (1.f / NN);
        float var = sq * (1.f / NN) - mu * mu;
        float rs = rsqrtf(var + EPS);
        float sc = rs * gamma[t];
        s_sc[t] = sc;
        s_sh[t] = beta[t] - mu * sc;
    }
    __syncthreads();

    int half = t >> 5;          // 0..7
    int sl = t & 31;
    int n0 = blockIdx.x * POOL_CHUNK + half * 32;
    if (n0 >= NN) return;
    int n1 = n0 + 32; if (n1 > NN) n1 = NN;

    const uintv2* a64 = reinterpret_cast<const uintv2*>(agg);
    float sc0 = s_sc[sl * 4 + 0], sh0 = s_sh[sl * 4 + 0];
    float sc1 = s_sc[sl * 4 + 1], sh1 = s_sh[sl * 4 + 1];
    float sc2 = s_sc[sl * 4 + 2], sh2 = s_sh[sl * 4 + 2];
    float sc3 = s_sc[sl * 4 + 3], sh3 = s_sh[sl * 4 + 3];

    int gcur = batch[n0];
    float a0 = 0.f, a1 = 0.f, a2 = 0.f, a3 = 0.f;
    for (int i = n0; i < n1; i++) {
        int g = batch[i];
        if (g != gcur) {
            atomicAdd(&pooled[(size_t)gcur * DH + sl * 4 + 0], a0);
            atomicAdd(&pooled[(size_t)gcur * DH + sl * 4 + 1], a1);
            atomicAdd(&pooled[(size_t)gcur * DH + sl * 4 + 2], a2);
            atomicAdd(&pooled[(size_t)gcur * DH + sl * 4 + 3], a3);
            a0 = a1 = a2 = a3 = 0.f; gcur = g;
        }
        uintv2 v = a64[(size_t)i * 32 + sl];
        a0 += fmaxf(blo(v.x) * sc0 + sh0, 0.f);
        a1 += fmaxf(bhi(v.x) * sc1 + sh1, 0.f);
        a2 += fmaxf(blo(v.y) * sc2 + sh2, 0.f);
        a3 += fmaxf(bhi(v.y) * sc3 + sh3, 0.f);
    }
    atomicAdd(&pooled[(size_t)gcur * DH + sl * 4 + 0], a0);
    atomicAdd(&pooled[(size_t)gcur * DH + sl * 4 + 1], a1);
    atomicAdd(&pooled[(size_t)gcur * DH + sl * 4 + 2], a2);
    atomicAdd(&pooled[(size_t)gcur * DH + sl * 4 + 3], a3);
}

// ---------------- Head ----------------

__global__ __launch_bounds__(128) void k_head(const float* __restrict__ pooled, const int* __restrict__ gcnt,
                                              const float* __restrict__ fw1, const float* __restrict__ fb1,
                                              const float* __restrict__ fw2, const float* __restrict__ fb2,
                                              float* __restrict__ out) {
    __shared__ float p[DH];
    __shared__ float z[DH];
    int g = blockIdx.x;
    int j = threadIdx.x;
    float cnt = (float)max(gcnt[g], 1);
    p[j] = pooled[(size_t)g * DH + j] / cnt;
    __syncthreads();
    float a = fb1[j];
    for (int k = 0; k < DH; k++) a += p[k] * fw1[k * DH + j];
    z[j] = fmaxf(a, 0.f);
    __syncthreads();
    if (j < DOUT) {
        float l = fb2[j];
        for (int k = 0; k < DH; k++) l += z[k] * fw2[k * DOUT + j];
        float m = l;
        for (int o = 16; o; o >>= 1) m = fmaxf(m, __shfl_xor(m, o, 32));
        float e = expf(l - m);
        float s = e;
        for (int o = 16; o; o >>= 1) s += __shfl_xor(s, o, 32);
        out[(size_t)g * DOUT + j] = e / s;
    }
}

// ---------------- launch ----------------

static inline char* align256p(char* p) {
    return (char*)(((uintptr_t)p + 255) & ~(uintptr_t)255);
}

extern "C" void kernel_launch(void* const* d_in, const int* in_sizes, int n_in,
                              void* d_out, int out_size, void* d_ws, size_t ws_size,
                              hipStream_t stream) {
    const float* x     = (const float*)d_in[0];
    const int*   ei    = (const int*)d_in[1];    // int32 per harness convention
    const int*   batch = (const int*)d_in[2];
    const float* W1    = (const float*)d_in[3];
    const float* W2    = (const float*)d_in[5];
    const float* g1    = (const float*)d_in[7];
    const float* be1   = (const float*)d_in[8];
    const float* g2    = (const float*)d_in[9];
    const float* be2   = (const float*)d_in[10];
    const float* fw1   = (const float*)d_in[11];
    const float* fb1   = (const float*)d_in[12];
    const float* fw2   = (const float*)d_in[13];
    const float* fb2   = (const float*)d_in[14];
    float* out = (float*)d_out;

    // workspace carve-up
    char* w = (char*)d_ws;
    unsigned short* hbuf = (unsigned short*)w;  w += (size_t)NN * DH * 2;
    unsigned short* abuf = (unsigned short*)w;  w += (size_t)NN * DH * 2;
    int*   csr    = (int*)w;    w += (size_t)NE * 4;
    int*   rowptr = (int*)w;    w += (size_t)(NN + 1) * 4;  w = align256p(w);
    float* dinv   = (float*)w;  w += (size_t)NN * 4;
    int*   bsum   = (int*)w;    w += 512 * 4;
    unsigned short* WT1g = (unsigned short*)w;  w += (size_t)DH * DH * 2;
    unsigned short* WT2g = (unsigned short*)w;  w += (size_t)DH * DH * 2;
    w = align256p(w);
    char* zstart  = w;
    int*   cnt    = (int*)w;    w += (size_t)NN * 4;   // also the fill cursor
    int*   gfirst = (int*)w;    w += 64 * 4;
    int*   glast  = (int*)w;    w += 64 * 4;
    int*   gcnt   = (int*)w;    w += 64 * 4;
    float* stats1 = (float*)w;  w += (size_t)NBUCKET * 256 * 4;
    float* stats2 = (float*)w;  w += (size_t)NBUCKET * 256 * 4;
    float* pooled = (float*)w;  w += (size_t)NG * DH * 4;
    size_t zbytes = (size_t)(w - zstart);
    size_t need = (size_t)(w - (char*)d_ws);
    if (ws_size < need) return;   // diagnostic: clean absmax-fail instead of a fault

    hipMemsetAsync(zstart, 0, zbytes, stream);

    k_prep<<<PREP_COUNT_BLKS + PREP_GB_BLKS + PREP_PW_BLKS, 256, 0, stream>>>(
        ei + NE, cnt, batch, gfirst, glast, W1, W2, WT1g, WT2g);
    k_scan_partial<<<SCAN_NB, 256, 0, stream>>>(cnt, bsum);
    k_scan_final<<<SCAN_NB, 256, 0, stream>>>(cnt, bsum, rowptr, dinv, gfirst, glast, gcnt);
    k_fill<<<1024, 256, 0, stream>>>(ei, cnt, csr);

    int gemm_grid = (NN + 127) / 128;   // 782

    // layer 1 (output pre-scaled by dinv)
    k_gemm<false, float><<<gemm_grid, 256, 0, stream>>>(x, WT1g, hbuf, dinv, nullptr, nullptr, nullptr);
    k_aggregate<<<AGG_BLOCKS, 128, 0, stream>>>(hbuf, rowptr, csr, dinv, abuf, stats1);

    // layer 2 (BN1 params computed in-block from stats1; BN1+ReLU fused into A-load)
    k_gemm<true, unsigned short><<<gemm_grid, 256, 0, stream>>>(abuf, WT2g, hbuf, dinv, stats1, g1, be1);
    k_aggregate<<<AGG_BLOCKS, 128, 0, stream>>>(hbuf, rowptr, csr, dinv, abuf, stats2);

    // pool (BN2 params computed in-block, BN2+ReLU fused) + head
    int pool_grid = (NN + POOL_CHUNK - 1) / POOL_CHUNK;   // 391
    k_pool<<<pool_grid, 256, 0, stream>>>(abuf, batch, stats2, g2, be2, pooled);
    k_head<<<NG, 128, 0, stream>>>(pooled, gcnt, fw1, fb1, fw2, fb2, out);
}